// Round 1
// baseline (741.884 us; speedup 1.0000x reference)
//
#include <hip/hip_runtime.h>
#include <hip/hip_bf16.h>

#define B_N 65536
#define M_N 1000000
#define E_N 1310720
#define IN_D 64
#define OUT_D 32

__device__ __forceinline__ unsigned short f2bf(float f) {
  unsigned u = __float_as_uint(f);
  u += 0x7fffu + ((u >> 16) & 1u);
  return (unsigned short)(u >> 16);
}
__device__ __forceinline__ unsigned pk2(float a, float b) {
  return (unsigned)f2bf(a) | ((unsigned)f2bf(b) << 16);
}

// Kernel 1: x = emb[uids]; h_bal = x@W_bal (bf16), h_unbal = x@W_unbal (bf16);
// adst = h . a[32:], asrc = h . a[:32] (asrc only for nodes < B).
// One thread per node; W staged in LDS, broadcast-read as float4.
__global__ __launch_bounds__(256) void k_hproj(
    const float* __restrict__ emb,
    const float* __restrict__ Wb, const float* __restrict__ ab,
    const float* __restrict__ Wu, const float* __restrict__ au,
    const int* __restrict__ uids,
    unsigned short* __restrict__ hb, unsigned short* __restrict__ hu,
    float* __restrict__ adb, float* __restrict__ adu,
    float* __restrict__ asb, float* __restrict__ asu)
{
  __shared__ float sWb[IN_D][OUT_D];
  __shared__ float sWu[IN_D][OUT_D];
  __shared__ float sab[2 * OUT_D];
  __shared__ float sau[2 * OUT_D];
  for (int i = threadIdx.x; i < IN_D * OUT_D; i += 256) {
    sWb[i >> 5][i & 31] = Wb[i];
    sWu[i >> 5][i & 31] = Wu[i];
  }
  if (threadIdx.x < 2 * OUT_D) {
    sab[threadIdx.x] = ab[threadIdx.x];
    sau[threadIdx.x] = au[threadIdx.x];
  }
  __syncthreads();

  int n = blockIdx.x * 256 + threadIdx.x;
  if (n >= M_N) return;
  int uid = uids[n];
  const float4* __restrict__ xr = (const float4*)(emb + (size_t)uid * IN_D);

  float4 x[16];
  #pragma unroll
  for (int kc = 0; kc < 16; ++kc) x[kc] = xr[kc];

  float accb[OUT_D], accu[OUT_D];
  #pragma unroll
  for (int j = 0; j < OUT_D; ++j) { accb[j] = 0.f; accu[j] = 0.f; }

  #pragma unroll
  for (int kc = 0; kc < 16; ++kc) {
    #pragma unroll
    for (int dk = 0; dk < 4; ++dk) {
      int k = kc * 4 + dk;
      float xk = (dk == 0) ? x[kc].x : (dk == 1) ? x[kc].y : (dk == 2) ? x[kc].z : x[kc].w;
      const float4* wb4 = (const float4*)(&sWb[k][0]);
      const float4* wu4 = (const float4*)(&sWu[k][0]);
      #pragma unroll
      for (int j4 = 0; j4 < 8; ++j4) {
        float4 wb = wb4[j4];
        float4 wu = wu4[j4];
        accb[4 * j4 + 0] = fmaf(xk, wb.x, accb[4 * j4 + 0]);
        accb[4 * j4 + 1] = fmaf(xk, wb.y, accb[4 * j4 + 1]);
        accb[4 * j4 + 2] = fmaf(xk, wb.z, accb[4 * j4 + 2]);
        accb[4 * j4 + 3] = fmaf(xk, wb.w, accb[4 * j4 + 3]);
        accu[4 * j4 + 0] = fmaf(xk, wu.x, accu[4 * j4 + 0]);
        accu[4 * j4 + 1] = fmaf(xk, wu.y, accu[4 * j4 + 1]);
        accu[4 * j4 + 2] = fmaf(xk, wu.z, accu[4 * j4 + 2]);
        accu[4 * j4 + 3] = fmaf(xk, wu.w, accu[4 * j4 + 3]);
      }
    }
  }

  float adotb = 0.f, adotu = 0.f, asrcb = 0.f, asrcu = 0.f;
  #pragma unroll
  for (int j = 0; j < OUT_D; ++j) {
    asrcb = fmaf(accb[j], sab[j], asrcb);
    adotb = fmaf(accb[j], sab[OUT_D + j], adotb);
    asrcu = fmaf(accu[j], sau[j], asrcu);
    adotu = fmaf(accu[j], sau[OUT_D + j], adotu);
  }
  adb[n] = adotb;
  adu[n] = adotu;
  if (n < B_N) { asb[n] = asrcb; asu[n] = asrcu; }

  uint4* hb4 = (uint4*)(hb + (size_t)n * OUT_D);
  uint4* hu4 = (uint4*)(hu + (size_t)n * OUT_D);
  #pragma unroll
  for (int q = 0; q < 4; ++q) {
    uint4 v, w;
    v.x = pk2(accb[8 * q + 0], accb[8 * q + 1]);
    v.y = pk2(accb[8 * q + 2], accb[8 * q + 3]);
    v.z = pk2(accb[8 * q + 4], accb[8 * q + 5]);
    v.w = pk2(accb[8 * q + 6], accb[8 * q + 7]);
    w.x = pk2(accu[8 * q + 0], accu[8 * q + 1]);
    w.y = pk2(accu[8 * q + 2], accu[8 * q + 3]);
    w.z = pk2(accu[8 * q + 4], accu[8 * q + 5]);
    w.w = pk2(accu[8 * q + 6], accu[8 * q + 7]);
    hb4[q] = v;
    hu4[q] = w;
  }
}

// Kernel 2: edge aggregation. One 32-lane group per edge (2 edges/wave).
// e = exp(-leaky_relu(asrc[r] + adst[c])); num[r,:] += e*h[c,:]; den[r] += e.
__global__ __launch_bounds__(256) void k_edge(
    const int* __restrict__ selfc,
    const int* __restrict__ erows, const int* __restrict__ ecols,
    const unsigned short* __restrict__ h,
    const float* __restrict__ adst, const float* __restrict__ asrc,
    float* __restrict__ num, float* __restrict__ den)
{
  int g = blockIdx.x * 8 + (threadIdx.x >> 5);
  int lane = threadIdx.x & 31;
  if (g >= B_N + E_N) return;
  int r, c;
  if (g < B_N) { r = g; c = selfc[g]; }
  else { r = erows[g - B_N]; c = ecols[g - B_N]; }
  float s = asrc[r] + adst[c];
  float sc = s > 0.f ? s : 0.2f * s;
  float ev = __expf(-sc);
  float hv = __uint_as_float(((unsigned)h[(size_t)c * OUT_D + lane]) << 16);
  atomicAdd(num + (((size_t)r) << 5) + lane, ev * hv);
  if (lane == 0) atomicAdd(den + r, ev);
}

// Kernel 3: out = elu(num/den) for both branches.
__global__ __launch_bounds__(256) void k_fin(
    const float* __restrict__ numb, const float* __restrict__ denb,
    const float* __restrict__ numu, const float* __restrict__ denu,
    float* __restrict__ out)
{
  int i = blockIdx.x * 256 + threadIdx.x;
  if (i >= B_N * OUT_D) return;
  int r = i >> 5;
  float xb = numb[i] / denb[r];
  out[i] = (xb > 0.f) ? xb : (__expf(xb) - 1.f);
  float xu = numu[i] / denu[r];
  out[B_N * OUT_D + i] = (xu > 0.f) ? xu : (__expf(xu) - 1.f);
}

extern "C" void kernel_launch(void* const* d_in, const int* in_sizes, int n_in,
                              void* d_out, int out_size, void* d_ws, size_t ws_size,
                              hipStream_t stream) {
  const float* emb = (const float*)d_in[0];
  const float* Wb  = (const float*)d_in[1];
  const float* ab  = (const float*)d_in[2];
  const float* Wu  = (const float*)d_in[3];
  const float* au  = (const float*)d_in[4];
  const int* uids  = (const int*)d_in[5];
  const int* selfc = (const int*)d_in[6];
  const int* prow  = (const int*)d_in[7];
  const int* pcol  = (const int*)d_in[8];
  const int* nrow  = (const int*)d_in[9];
  const int* ncol  = (const int*)d_in[10];
  float* out = (float*)d_out;

  char* ws = (char*)d_ws;
  size_t off = 0;
  auto alloc = [&](size_t bytes) -> void* {
    void* p = ws + off;
    off += (bytes + 255) & ~(size_t)255;
    return p;
  };
  unsigned short* hb = (unsigned short*)alloc((size_t)M_N * OUT_D * 2);
  unsigned short* hu = (unsigned short*)alloc((size_t)M_N * OUT_D * 2);
  float* adb = (float*)alloc((size_t)M_N * 4);
  float* adu = (float*)alloc((size_t)M_N * 4);
  float* asb = (float*)alloc((size_t)B_N * 4);
  float* asu = (float*)alloc((size_t)B_N * 4);
  char* zbase = ws + off;
  float* numb = (float*)alloc((size_t)B_N * OUT_D * 4);
  float* numu = (float*)alloc((size_t)B_N * OUT_D * 4);
  float* denb = (float*)alloc((size_t)B_N * 4);
  float* denu = (float*)alloc((size_t)B_N * 4);
  size_t zbytes = (size_t)((ws + off) - zbase);

  hipMemsetAsync(zbase, 0, zbytes, stream);

  k_hproj<<<(M_N + 255) / 256, 256, 0, stream>>>(emb, Wb, ab, Wu, au, uids,
                                                 hb, hu, adb, adu, asb, asu);

  int egroups = B_N + E_N;
  int eblocks = (egroups + 7) / 8;
  k_edge<<<eblocks, 256, 0, stream>>>(selfc, prow, pcol, hb, adb, asb, numb, denb);
  k_edge<<<eblocks, 256, 0, stream>>>(selfc, nrow, ncol, hu, adu, asu, numu, denu);

  k_fin<<<(B_N * OUT_D + 255) / 256, 256, 0, stream>>>(numb, denb, numu, denu, out);
}